// Round 7
// baseline (1281.445 us; speedup 1.0000x reference)
//
#include <hip/hip_runtime.h>
#include <cmath>

#define B_ 4
#define C_ 256
#define P_ 4096   // H*W
#define N_ 4096   // tokens per batch (raw-reshape token count)

typedef __bf16 bf16x8 __attribute__((ext_vector_type(8)));
typedef __bf16 bf16x4 __attribute__((ext_vector_type(4)));
typedef float  f32x4  __attribute__((ext_vector_type(4)));

// ---------------------------------------------------------------------------
// Projection GEMM (fp32 compute) with bf16 hi/lo split output.
// Y viewed linearly IS the (n,c) token matrix (raw-reshape identity).
// ---------------------------------------------------------------------------
__global__ __launch_bounds__(256) void proj_kernel(
    const float* __restrict__ X, const float* __restrict__ W,
    const float* __restrict__ bias,
    __bf16* __restrict__ Yh, __bf16* __restrict__ Yl)
{
    const int p0 = blockIdx.x * 64;
    const int o0 = blockIdx.y * 64;
    const int b  = blockIdx.z;

    const float* Xb = X + (size_t)b * C_ * P_;
    const size_t ybase = (size_t)b * C_ * P_;

    __shared__ float WsT[32][68];
    __shared__ float Xs[32][64];

    const int tid = threadIdx.x;
    const int tx = tid & 15, ty = tid >> 4;

    float acc[4][4] = {};

    for (int kk = 0; kk < C_; kk += 32) {
        __syncthreads();
        #pragma unroll
        for (int i = 0; i < 8; ++i) {
            int flat = tid + i * 256;
            int r = flat >> 5, c = flat & 31;
            WsT[c][r] = W[(o0 + r) * C_ + (kk + c)];
        }
        #pragma unroll
        for (int i = 0; i < 8; ++i) {
            int flat = tid + i * 256;
            int r = flat >> 6, c = flat & 63;
            Xs[r][c] = Xb[(size_t)(kk + r) * P_ + (p0 + c)];
        }
        __syncthreads();
        #pragma unroll
        for (int k = 0; k < 32; ++k) {
            float4 a4 = *(const float4*)&WsT[k][ty * 4];
            float4 x4 = *(const float4*)&Xs[k][tx * 4];
            const float av[4] = {a4.x, a4.y, a4.z, a4.w};
            const float xv[4] = {x4.x, x4.y, x4.z, x4.w};
            #pragma unroll
            for (int i = 0; i < 4; ++i)
                #pragma unroll
                for (int j = 0; j < 4; ++j)
                    acc[i][j] += av[i] * xv[j];
        }
    }

    #pragma unroll
    for (int i = 0; i < 4; ++i) {
        float bv = bias[o0 + ty * 4 + i];
        bf16x4 h, l;
        #pragma unroll
        for (int j = 0; j < 4; ++j) {
            float y  = acc[i][j] + bv;
            __bf16 hh = (__bf16)y;
            __bf16 ll = (__bf16)(y - (float)hh);
            h[j] = hh; l[j] = ll;
        }
        size_t off = ybase + (size_t)(o0 + ty * 4 + i) * P_ + p0 + tx * 4;
        *(bf16x4*)&Yh[off] = h;
        *(bf16x4*)&Yl[off] = l;
    }
}

// ---------------------------------------------------------------------------
// Transpose V (n,c) -> Vt (c,n), bf16 bits. grid (64, 4, 8): z = b*2 + buf.
// ---------------------------------------------------------------------------
__global__ __launch_bounds__(256) void transpose_kernel(
    const ushort* __restrict__ SrcH, const ushort* __restrict__ SrcL,
    ushort* __restrict__ DstH, ushort* __restrict__ DstL)
{
    const int n0 = blockIdx.x * 64;
    const int c0 = blockIdx.y * 64;
    const int b  = blockIdx.z >> 1;
    const int bf = blockIdx.z & 1;

    const ushort* src = (bf ? SrcL : SrcH) + (size_t)b * N_ * C_;
    ushort*       dst = (bf ? DstL : DstH) + (size_t)b * N_ * C_;

    __shared__ ushort T[64][65];
    const int tid = threadIdx.x;

    #pragma unroll
    for (int it = 0; it < 4; ++it) {
        int e = tid + it * 256;
        int r = e >> 4, c4 = (e & 15) * 4;
        *(ushort4*)&T[r][c4] = *(const ushort4*)&src[(size_t)(n0 + r) * C_ + c0 + c4];
    }
    __syncthreads();
    #pragma unroll
    for (int it = 0; it < 4; ++it) {
        int e = tid + it * 256;
        int cr = e >> 4, nl = (e & 15) * 4;
        ushort4 v;
        v.x = T[nl + 0][cr]; v.y = T[nl + 1][cr];
        v.z = T[nl + 2][cr]; v.w = T[nl + 3][cr];
        *(ushort4*)&dst[(size_t)(c0 + cr) * N_ + n0 + nl] = v;
    }
}

// ---------------------------------------------------------------------------
// Split-bf16 MFMA flash attention with m-split (flash-decoding).
// grid (N/64, SPLIT, B), block 256 (4 waves x 16 q-rows).
// Each block covers m in [s*mlen, (s+1)*mlen). SPLIT==1 writes normalized
// output directly; else unnormalized partial O + (m,l) per row to ws.
// ---------------------------------------------------------------------------
__global__ __launch_bounds__(256) void attn_kernel(
    const __bf16* __restrict__ Qh, const __bf16* __restrict__ Ql,
    const __bf16* __restrict__ Kh, const __bf16* __restrict__ Kl,
    const __bf16* __restrict__ Vth, const __bf16* __restrict__ Vtl,
    float* __restrict__ O, float* __restrict__ OP, float* __restrict__ ML,
    int SPLIT, int mlen)
{
    const int b    = blockIdx.z;
    const int s    = blockIdx.y;
    const int n0   = blockIdx.x * 64;
    const int m_lo = s * mlen;
    const size_t base = (size_t)b * N_ * C_;

    const int tid  = threadIdx.x;
    const int w    = tid >> 6;
    const int lane = tid & 63;
    const int l15  = lane & 15;
    const int lg   = lane >> 4;

    __shared__ __align__(16) __bf16 Pl[4][2][16][72];

    const __bf16* qh_p = Qh + base + (size_t)(n0 + w * 16 + l15) * C_ + lg * 8;
    const __bf16* ql_p = Ql + base + (size_t)(n0 + w * 16 + l15) * C_ + lg * 8;
    bf16x8 qfh[8], qfl[8];
    #pragma unroll
    for (int k = 0; k < 8; ++k) {
        qfh[k] = *(const bf16x8*)(qh_p + k * 32);
        qfl[k] = *(const bf16x8*)(ql_p + k * 32);
    }

    f32x4 oc[16];
    #pragma unroll
    for (int c = 0; c < 16; ++c) oc[c] = (f32x4){0.f, 0.f, 0.f, 0.f};
    float m_run[4] = {-1e30f, -1e30f, -1e30f, -1e30f};
    float l_run[4] = {0.f, 0.f, 0.f, 0.f};

    for (int mt0 = 0; mt0 < mlen; mt0 += 64) {
        const int mt = m_lo + mt0;
        // ---------------- S = Q K^T ----------------
        f32x4 sacc[4];
        #pragma unroll
        for (int js = 0; js < 4; ++js) sacc[js] = (f32x4){0.f, 0.f, 0.f, 0.f};

        const __bf16* kh_p = Kh + base + (size_t)(mt + l15) * C_ + lg * 8;
        const __bf16* kl_p = Kl + base + (size_t)(mt + l15) * C_ + lg * 8;

        #pragma unroll
        for (int kk = 0; kk < 8; ++kk) {
            #pragma unroll
            for (int js = 0; js < 4; ++js) {
                bf16x8 kfh = *(const bf16x8*)(kh_p + js * 16 * C_ + kk * 32);
                bf16x8 kfl = *(const bf16x8*)(kl_p + js * 16 * C_ + kk * 32);
                sacc[js] = __builtin_amdgcn_mfma_f32_16x16x32_bf16(qfh[kk], kfh, sacc[js], 0, 0, 0);
                sacc[js] = __builtin_amdgcn_mfma_f32_16x16x32_bf16(qfh[kk], kfl, sacc[js], 0, 0, 0);
                sacc[js] = __builtin_amdgcn_mfma_f32_16x16x32_bf16(qfl[kk], kfh, sacc[js], 0, 0, 0);
            }
        }

        // ---------------- online softmax ----------------
        float scale_[4];
        #pragma unroll
        for (int r = 0; r < 4; ++r) {
            float mx = fmaxf(fmaxf(sacc[0][r], sacc[1][r]), fmaxf(sacc[2][r], sacc[3][r]));
            #pragma unroll
            for (int d = 1; d < 16; d <<= 1)
                mx = fmaxf(mx, __shfl_xor(mx, d, 64));
            float mnew = fmaxf(m_run[r], mx);
            scale_[r] = __expf(m_run[r] - mnew);
            float ss = 0.f;
            #pragma unroll
            for (int js = 0; js < 4; ++js) {
                float pv = __expf(sacc[js][r] - mnew);
                sacc[js][r] = pv;
                ss += pv;
            }
            #pragma unroll
            for (int d = 1; d < 16; d <<= 1)
                ss += __shfl_xor(ss, d, 64);
            l_run[r] = l_run[r] * scale_[r] + ss;
            m_run[r] = mnew;
        }

        #pragma unroll
        for (int js = 0; js < 4; ++js)
            #pragma unroll
            for (int r = 0; r < 4; ++r) {
                float pv = sacc[js][r];
                __bf16 hh = (__bf16)pv;
                __bf16 ll = (__bf16)(pv - (float)hh);
                Pl[w][0][lg * 4 + r][js * 16 + l15] = hh;
                Pl[w][1][lg * 4 + r][js * 16 + l15] = ll;
            }

        #pragma unroll
        for (int c = 0; c < 16; ++c)
            #pragma unroll
            for (int r = 0; r < 4; ++r)
                oc[c][r] *= scale_[r];

        __syncthreads();

        bf16x8 pah0 = *(const bf16x8*)&Pl[w][0][l15][lg * 8];
        bf16x8 pah1 = *(const bf16x8*)&Pl[w][0][l15][32 + lg * 8];
        bf16x8 pal0 = *(const bf16x8*)&Pl[w][1][l15][lg * 8];
        bf16x8 pal1 = *(const bf16x8*)&Pl[w][1][l15][32 + lg * 8];

        // ---------------- O += P V ----------------
        const __bf16* vh_p = Vth + base + (size_t)l15 * N_ + mt + lg * 8;
        const __bf16* vl_p = Vtl + base + (size_t)l15 * N_ + mt + lg * 8;
        #pragma unroll
        for (int cs = 0; cs < 16; ++cs) {
            const __bf16* vh_c = vh_p + (size_t)cs * 16 * N_;
            const __bf16* vl_c = vl_p + (size_t)cs * 16 * N_;
            bf16x8 vh0 = *(const bf16x8*)(vh_c);
            bf16x8 vh1 = *(const bf16x8*)(vh_c + 32);
            bf16x8 vl0 = *(const bf16x8*)(vl_c);
            bf16x8 vl1 = *(const bf16x8*)(vl_c + 32);
            f32x4 a = oc[cs];
            a = __builtin_amdgcn_mfma_f32_16x16x32_bf16(pah0, vh0, a, 0, 0, 0);
            a = __builtin_amdgcn_mfma_f32_16x16x32_bf16(pah0, vl0, a, 0, 0, 0);
            a = __builtin_amdgcn_mfma_f32_16x16x32_bf16(pal0, vh0, a, 0, 0, 0);
            a = __builtin_amdgcn_mfma_f32_16x16x32_bf16(pah1, vh1, a, 0, 0, 0);
            a = __builtin_amdgcn_mfma_f32_16x16x32_bf16(pah1, vl1, a, 0, 0, 0);
            a = __builtin_amdgcn_mfma_f32_16x16x32_bf16(pal1, vh1, a, 0, 0, 0);
            oc[cs] = a;
        }
    }

    // ---------------- epilogue ----------------
    if (SPLIT == 1) {
        float inv[4];
        #pragma unroll
        for (int r = 0; r < 4; ++r) inv[r] = 1.0f / l_run[r];
        #pragma unroll
        for (int cs = 0; cs < 16; ++cs)
            #pragma unroll
            for (int r = 0; r < 4; ++r)
                O[base + (size_t)(n0 + w * 16 + lg * 4 + r) * C_ + cs * 16 + l15] =
                    oc[cs][r] * inv[r];
    } else {
        const size_t prow0 = (size_t)(b * SPLIT + s) * N_;
        #pragma unroll
        for (int cs = 0; cs < 16; ++cs)
            #pragma unroll
            for (int r = 0; r < 4; ++r)
                OP[(prow0 + n0 + w * 16 + lg * 4 + r) * C_ + cs * 16 + l15] =
                    oc[cs][r];
        if (l15 == 0) {
            #pragma unroll
            for (int r = 0; r < 4; ++r) {
                size_t mi = (prow0 + n0 + w * 16 + lg * 4 + r) * 2;
                ML[mi]     = m_run[r];
                ML[mi + 1] = l_run[r];
            }
        }
    }
}

// ---------------------------------------------------------------------------
// Combine SPLIT partials: out = sum_s OP_s * exp(m_s - M) / L.
// ---------------------------------------------------------------------------
__global__ __launch_bounds__(256) void combine_kernel(
    const float* __restrict__ OP, const float* __restrict__ ML,
    float* __restrict__ out, int SPLIT)
{
    const size_t total = (size_t)B_ * N_ * C_ / 4;
    for (size_t e = (size_t)blockIdx.x * blockDim.x + threadIdx.x; e < total;
         e += (size_t)gridDim.x * blockDim.x) {
        size_t row = e / (C_ / 4);        // b*N + n
        size_t c4  = e % (C_ / 4);
        int b = (int)(row >> 12);         // N_ = 4096
        int n = (int)(row & (N_ - 1));

        float ms[8], ls[8];
        float M = -1e30f;
        for (int s = 0; s < SPLIT; ++s) {
            size_t mi = ((size_t)(b * SPLIT + s) * N_ + n) * 2;
            ms[s] = ML[mi]; ls[s] = ML[mi + 1];
            M = fmaxf(M, ms[s]);
        }
        float L = 0.f;
        float wgt[8];
        for (int s = 0; s < SPLIT; ++s) {
            wgt[s] = __expf(ms[s] - M);
            L += ls[s] * wgt[s];
        }
        float invL = 1.0f / L;

        float4 acc = {0.f, 0.f, 0.f, 0.f};
        for (int s = 0; s < SPLIT; ++s) {
            const float4 v = *(const float4*)&OP[(((size_t)(b * SPLIT + s) * N_ + n) * C_) + c4 * 4];
            acc.x += v.x * wgt[s]; acc.y += v.y * wgt[s];
            acc.z += v.z * wgt[s]; acc.w += v.w * wgt[s];
        }
        acc.x *= invL; acc.y *= invL; acc.z *= invL; acc.w *= invL;
        *(float4*)&out[e * 4] = acc;
    }
}

// ---------------------------------------------------------------------------
extern "C" void kernel_launch(void* const* d_in, const int* in_sizes, int n_in,
                              void* d_out, int out_size, void* d_ws, size_t ws_size,
                              hipStream_t stream)
{
    const float* tgt = (const float*)d_in[0];
    const float* src = (const float*)d_in[1];
    const float* qw  = (const float*)d_in[2];
    const float* qb  = (const float*)d_in[3];
    const float* kw  = (const float*)d_in[4];
    const float* kb  = (const float*)d_in[5];
    const float* vw  = (const float*)d_in[6];
    const float* vb  = (const float*)d_in[7];
    float* out = (float*)d_out;

    // ws: [bf16 x6: Qh Ql Kh Kl Vth Vtl = 50.3MB] [OP: SPLIT*16.8MB f32] [ML]
    const size_t SZ = (size_t)B_ * N_ * C_;
    __bf16* w0 = (__bf16*)d_ws;
    __bf16* w1 = w0 + SZ;
    __bf16* w2 = w1 + SZ;
    __bf16* w3 = w2 + SZ;
    __bf16* w4 = w3 + SZ;
    __bf16* w5 = w4 + SZ;

    const size_t qkv_bytes = 6 * SZ * sizeof(__bf16);
    auto need = [&](int s) {
        return qkv_bytes + (size_t)s * SZ * 4 + (size_t)s * B_ * N_ * 2 * 4;
    };
    int SPLIT = 1;
    if (ws_size >= need(4)) SPLIT = 4;
    else if (ws_size >= need(2)) SPLIT = 2;

    float* OP = (float*)((char*)d_ws + qkv_bytes);
    float* ML = OP + (size_t)SPLIT * SZ;

    dim3 pgrid(P_ / 64, C_ / 64, B_);
    // 1) V projection -> Vnc (into future-Q region)
    proj_kernel<<<pgrid, 256, 0, stream>>>(src, vw, vb, w0, w1);
    // 2) transpose Vnc -> Vt
    dim3 tgrid(N_ / 64, C_ / 64, B_ * 2);
    transpose_kernel<<<tgrid, 256, 0, stream>>>(
        (const ushort*)w0, (const ushort*)w1, (ushort*)w4, (ushort*)w5);
    // 3) Q projection (overwrites dead Vnc)
    proj_kernel<<<pgrid, 256, 0, stream>>>(tgt, qw, qb, w0, w1);
    // 4) K projection
    proj_kernel<<<pgrid, 256, 0, stream>>>(src, kw, kb, w2, w3);
    // 5) attention (m-split)
    dim3 agrid(N_ / 64, SPLIT, B_);
    attn_kernel<<<agrid, 256, 0, stream>>>(w0, w1, w2, w3, w4, w5,
                                           out, OP, ML, SPLIT, N_ / SPLIT);
    // 6) combine partials
    if (SPLIT > 1)
        combine_kernel<<<2048, 256, 0, stream>>>(OP, ML, out, SPLIT);
}